// Round 1
// baseline (2190.035 us; speedup 1.0000x reference)
//
#include <hip/hip_runtime.h>

// Problem constants (fixed by the reference).
constexpr int U = 200000;
constexpr int I = 100000;
constexpr int N = 300000;   // U + I
constexpr int E = 9600000;
constexpr int D4 = 16;      // D=64 floats -> 16 float4 per row

constexpr int SCAN_BLOCK = 256;
constexpr int SCAN_ITEMS = 4;
constexpr int SCAN_CHUNK = SCAN_BLOCK * SCAN_ITEMS;  // 1024

// ---------------- CSR build ----------------

__global__ void hist_kernel(const int* __restrict__ row, int* __restrict__ counts, int e_cnt) {
    int e = blockIdx.x * blockDim.x + threadIdx.x;
    if (e < e_cnt) atomicAdd(&counts[row[e]], 1);
}

// Exclusive scan, phase 1: per-block scan + block totals.
// Also reused (grid=1, blockSums=nullptr) as the phase-2 scan of block totals
// (in-place safe: all reads happen before the first barrier, writes after the last).
__global__ void scan_phase1(const int* __restrict__ in, int* __restrict__ out,
                            int* __restrict__ blockSums, int n) {
    __shared__ int sdata[SCAN_BLOCK];
    int tid = threadIdx.x;
    int base = blockIdx.x * SCAN_CHUNK + tid * SCAN_ITEMS;
    int pref[SCAN_ITEMS];
    int sum = 0;
#pragma unroll
    for (int i = 0; i < SCAN_ITEMS; ++i) {
        int idx = base + i;
        int v = (idx < n) ? in[idx] : 0;
        pref[i] = sum;
        sum += v;
    }
    sdata[tid] = sum;
    __syncthreads();
    for (int off = 1; off < SCAN_BLOCK; off <<= 1) {
        int t = (tid >= off) ? sdata[tid - off] : 0;
        __syncthreads();
        sdata[tid] += t;
        __syncthreads();
    }
    int texcl = (tid == 0) ? 0 : sdata[tid - 1];
    if (tid == SCAN_BLOCK - 1 && blockSums) blockSums[blockIdx.x] = sdata[SCAN_BLOCK - 1];
#pragma unroll
    for (int i = 0; i < SCAN_ITEMS; ++i) {
        int idx = base + i;
        if (idx < n) out[idx] = texcl + pref[i];
    }
}

__global__ void scan_phase3(int* __restrict__ out, const int* __restrict__ blockSums, int n) {
    int base = blockIdx.x * SCAN_CHUNK + threadIdx.x * SCAN_ITEMS;
    int add = blockSums[blockIdx.x];
#pragma unroll
    for (int i = 0; i < SCAN_ITEMS; ++i) {
        int idx = base + i;
        if (idx < n) out[idx] += add;
    }
}

__global__ void scatter_kernel(const int* __restrict__ row, const int* __restrict__ col,
                               const float* __restrict__ vals, int* __restrict__ cursor,
                               int* __restrict__ colS, float* __restrict__ valsS, int e_cnt) {
    int e = blockIdx.x * blockDim.x + threadIdx.x;
    if (e < e_cnt) {
        int r = row[e];
        int pos = atomicAdd(&cursor[r], 1);
        colS[pos] = col[e];
        valsS[pos] = vals[e];
    }
}

// ---------------- SpMM ----------------
// 16 threads per node; each thread owns one float4 (4 of the 64 dims).

__global__ void spmm_l1(const int* __restrict__ rowPtr, const int* __restrict__ colS,
                        const float* __restrict__ valsS,
                        const float4* __restrict__ ue, const float4* __restrict__ ie,
                        float4* __restrict__ y) {
    int lane = threadIdx.x & 15;
    int n = blockIdx.x * 16 + (threadIdx.x >> 4);
    int s = rowPtr[n], t = rowPtr[n + 1];
    float ax = 0.f, ay = 0.f, az = 0.f, aw = 0.f;
    for (int e = s; e < t; ++e) {
        int c = colS[e];
        float v = valsS[e];
        float4 xv = (c < U) ? ue[(size_t)c * D4 + lane] : ie[(size_t)(c - U) * D4 + lane];
        ax = fmaf(v, xv.x, ax); ay = fmaf(v, xv.y, ay);
        az = fmaf(v, xv.z, az); aw = fmaf(v, xv.w, aw);
    }
    float4 o; o.x = ax; o.y = ay; o.z = az; o.w = aw;
    y[(size_t)n * D4 + lane] = o;
}

__global__ void spmm_mid(const int* __restrict__ rowPtr, const int* __restrict__ colS,
                         const float* __restrict__ valsS,
                         const float4* __restrict__ x, float4* __restrict__ y) {
    int lane = threadIdx.x & 15;
    int n = blockIdx.x * 16 + (threadIdx.x >> 4);
    int s = rowPtr[n], t = rowPtr[n + 1];
    float ax = 0.f, ay = 0.f, az = 0.f, aw = 0.f;
    for (int e = s; e < t; ++e) {
        int c = colS[e];
        float v = valsS[e];
        float4 xv = x[(size_t)c * D4 + lane];
        ax = fmaf(v, xv.x, ax); ay = fmaf(v, xv.y, ay);
        az = fmaf(v, xv.z, az); aw = fmaf(v, xv.w, aw);
    }
    float4 o; o.x = ax; o.y = ay; o.z = az; o.w = aw;
    y[(size_t)n * D4 + lane] = o;
}

// Layer-3 SpMM fused with the full output epilogue.
// out layout (float4 units): users[U*16] | items[I*16] | um0 um1 um2 (U*16 each) | im0 im1 im2 (I*16 each)
__global__ void spmm_final(const int* __restrict__ rowPtr, const int* __restrict__ colS,
                           const float* __restrict__ valsS,
                           const float4* __restrict__ h2, const float4* __restrict__ h1,
                           const float4* __restrict__ ue, const float4* __restrict__ ie,
                           float4* __restrict__ out) {
    int lane = threadIdx.x & 15;
    int n = blockIdx.x * 16 + (threadIdx.x >> 4);
    int s = rowPtr[n], t = rowPtr[n + 1];
    float ax = 0.f, ay = 0.f, az = 0.f, aw = 0.f;
    for (int e = s; e < t; ++e) {
        int c = colS[e];
        float v = valsS[e];
        float4 xv = h2[(size_t)c * D4 + lane];
        ax = fmaf(v, xv.x, ax); ay = fmaf(v, xv.y, ay);
        az = fmaf(v, xv.z, az); aw = fmaf(v, xv.w, aw);
    }
    size_t r16 = (size_t)n * D4 + lane;
    float4 e0 = (n < U) ? ue[r16] : ie[(size_t)(n - U) * D4 + lane];
    float4 a1 = h1[r16];
    float4 a2 = h2[r16];

    float c1x = e0.x + a1.x, c1y = e0.y + a1.y, c1z = e0.z + a1.z, c1w = e0.w + a1.w;
    float c2x = c1x + a2.x, c2y = c1y + a2.y, c2z = c1z + a2.z, c2w = c1w + a2.w;
    float c3x = c2x + ax,   c3y = c2y + ay,   c3z = c2z + az,   c3w = c2w + aw;

    float4 um0; um0.x = c1x * 0.5f; um0.y = c1y * 0.5f; um0.z = c1z * 0.5f; um0.w = c1w * 0.5f;
    float4 um1; um1.x = c2x / 3.0f; um1.y = c2y / 3.0f; um1.z = c2z / 3.0f; um1.w = c2w / 3.0f;
    float4 m;   m.x   = c3x * 0.25f; m.y  = c3y * 0.25f; m.z  = c3z * 0.25f; m.w  = c3w * 0.25f;

    constexpr size_t N16 = (size_t)N * D4;
    constexpr size_t U16 = (size_t)U * D4;
    constexpr size_t I16 = (size_t)I * D4;
    if (n < U) {
        size_t r = (size_t)n * D4 + lane;
        out[r] = m;                          // users
        out[N16 + r] = um0;                  // users_mean0
        out[N16 + U16 + r] = um1;            // users_mean1
        out[N16 + 2 * U16 + r] = m;          // users_mean2 == users
    } else {
        size_t r = (size_t)(n - U) * D4 + lane;
        out[U16 + r] = m;                    // items
        out[N16 + 3 * U16 + r] = um0;        // items_mean0
        out[N16 + 3 * U16 + I16 + r] = um1;  // items_mean1
        out[N16 + 3 * U16 + 2 * I16 + r] = m; // items_mean2 == items
    }
}

extern "C" void kernel_launch(void* const* d_in, const int* in_sizes, int n_in,
                              void* d_out, int out_size, void* d_ws, size_t ws_size,
                              hipStream_t stream) {
    const float* ue   = (const float*)d_in[0];
    const float* ie   = (const float*)d_in[1];
    const int*   row  = (const int*)d_in[2];
    const int*   col  = (const int*)d_in[3];
    const float* vals = (const float*)d_in[4];

    char* ws = (char*)d_ws;
    size_t off = 0;
    float* h1     = (float*)(ws + off); off += (size_t)N * 64 * 4;   // 76.8 MB
    float* h2     = (float*)(ws + off); off += (size_t)N * 64 * 4;   // 76.8 MB
    int*   counts = (int*)(ws + off);   off += (size_t)(N + 1) * 4;  // counts, then cursor
    int*   rowPtr = (int*)(ws + off);   off += (size_t)(N + 1) * 4;
    int*   bsums  = (int*)(ws + off);   off += 4096;
    int*   colS   = (int*)(ws + off);   off += (size_t)E * 4;        // 38.4 MB
    float* valsS  = (float*)(ws + off); off += (size_t)E * 4;        // 38.4 MB
    // total ~233 MB

    // ---- CSR build (deterministic work, rebuilt every call) ----
    hipMemsetAsync(counts, 0, (size_t)(N + 1) * 4, stream);
    hist_kernel<<<(E + 255) / 256, 256, 0, stream>>>(row, counts, E);
    const int nScan = N + 1;
    const int nB = (nScan + SCAN_CHUNK - 1) / SCAN_CHUNK;   // 293
    scan_phase1<<<nB, SCAN_BLOCK, 0, stream>>>(counts, rowPtr, bsums, nScan);
    scan_phase1<<<1, SCAN_BLOCK, 0, stream>>>(bsums, bsums, nullptr, nB);
    scan_phase3<<<nB, SCAN_BLOCK, 0, stream>>>(rowPtr, bsums, nScan);
    hipMemcpyAsync(counts, rowPtr, (size_t)N * 4, hipMemcpyDeviceToDevice, stream); // cursor
    scatter_kernel<<<(E + 255) / 256, 256, 0, stream>>>(row, col, vals, counts, colS, valsS, E);

    // ---- 3 SpMM layers (layer 3 fused with output epilogue) ----
    const int spmmBlocks = N / 16;  // 18750, 16 nodes per 256-thread block
    spmm_l1<<<spmmBlocks, 256, 0, stream>>>(rowPtr, colS, valsS,
                                            (const float4*)ue, (const float4*)ie, (float4*)h1);
    spmm_mid<<<spmmBlocks, 256, 0, stream>>>(rowPtr, colS, valsS,
                                             (const float4*)h1, (float4*)h2);
    spmm_final<<<spmmBlocks, 256, 0, stream>>>(rowPtr, colS, valsS,
                                               (const float4*)h2, (const float4*)h1,
                                               (const float4*)ue, (const float4*)ie,
                                               (float4*)d_out);
}

// Round 2
// 2072.974 us; speedup vs baseline: 1.0565x; 1.0565x over previous
//
#include <hip/hip_runtime.h>

// Problem constants (fixed by the reference).
constexpr int U = 200000;
constexpr int I = 100000;
constexpr int N = 300000;   // U + I
constexpr int E = 9600000;
constexpr int D4 = 16;      // D=64 floats -> 16 float4 per row

constexpr int SCAN_BLOCK = 256;
constexpr int SCAN_ITEMS = 4;
constexpr int SCAN_CHUNK = SCAN_BLOCK * SCAN_ITEMS;  // 1024

constexpr int NBKT = 32;            // coarse row-range buckets
constexpr int RSPAN = N / NBKT;     // 9375 rows per bucket -> 2.4MB edgeS window (fits 4MB XCD L2)
constexpr int P1_EDGES = 1024;      // edges staged per block in phase 1
constexpr int P1_THREADS = 256;
constexpr int P2_BPB = 256;         // blocks per bucket in phase 2

// ---------------- CSR build ----------------

__global__ void hist_kernel(const int* __restrict__ row, int* __restrict__ counts, int e_cnt) {
    int e = blockIdx.x * blockDim.x + threadIdx.x;
    if (e < e_cnt) atomicAdd(&counts[row[e]], 1);
}

// Exclusive scan, phase 1: per-block scan + block totals.
// Also reused (grid=1, blockSums=nullptr) as the phase-2 scan of block totals
// (in-place safe: all reads happen before the first barrier, writes after the last).
__global__ void scan_phase1(const int* __restrict__ in, int* __restrict__ out,
                            int* __restrict__ blockSums, int n) {
    __shared__ int sdata[SCAN_BLOCK];
    int tid = threadIdx.x;
    int base = blockIdx.x * SCAN_CHUNK + tid * SCAN_ITEMS;
    int pref[SCAN_ITEMS];
    int sum = 0;
#pragma unroll
    for (int i = 0; i < SCAN_ITEMS; ++i) {
        int idx = base + i;
        int v = (idx < n) ? in[idx] : 0;
        pref[i] = sum;
        sum += v;
    }
    sdata[tid] = sum;
    __syncthreads();
    for (int off = 1; off < SCAN_BLOCK; off <<= 1) {
        int t = (tid >= off) ? sdata[tid - off] : 0;
        __syncthreads();
        sdata[tid] += t;
        __syncthreads();
    }
    int texcl = (tid == 0) ? 0 : sdata[tid - 1];
    if (tid == SCAN_BLOCK - 1 && blockSums) blockSums[blockIdx.x] = sdata[SCAN_BLOCK - 1];
#pragma unroll
    for (int i = 0; i < SCAN_ITEMS; ++i) {
        int idx = base + i;
        if (idx < n) out[idx] = texcl + pref[i];
    }
}

__global__ void scan_phase3(int* __restrict__ out, const int* __restrict__ blockSums, int n) {
    int base = blockIdx.x * SCAN_CHUNK + threadIdx.x * SCAN_ITEMS;
    int add = blockSums[blockIdx.x];
#pragma unroll
    for (int i = 0; i < SCAN_ITEMS; ++i) {
        int idx = base + i;
        if (idx < n) out[idx] += add;
    }
}

__global__ void init_bkt(const int* __restrict__ rowPtr, int* __restrict__ bktCursor) {
    int t = threadIdx.x;
    if (t < NBKT) bktCursor[t] = rowPtr[t * RSPAN];
}

// Phase 1: LDS multisplit into 32 row-range buckets. Output: planar (r,c,v)
// bucket arenas (arena b = [rowPtr[b*RSPAN], rowPtr[(b+1)*RSPAN]) in edge index
// space; within-arena order arbitrary). Writes go out as contiguous per-bucket
// segments (~32 edges each) -> coalesced, no write amplification.
__global__ void bucket_kernel(const int* __restrict__ row, const int* __restrict__ col,
                              const float* __restrict__ vals, int* __restrict__ bktCursor,
                              int* __restrict__ rB, int* __restrict__ cB, float* __restrict__ vB) {
    __shared__ int cnt[NBKT];
    __shared__ int fill[NBKT];
    __shared__ int lofs[NBKT + 1];
    __shared__ int goff[NBKT];
    __shared__ int rS[P1_EDGES];
    __shared__ int cS[P1_EDGES];
    __shared__ float vS[P1_EDGES];
    __shared__ unsigned char bktS[P1_EDGES];

    int tid = threadIdx.x;
    int base = blockIdx.x * P1_EDGES;
    if (tid < NBKT) { cnt[tid] = 0; fill[tid] = 0; }
    __syncthreads();

    int r[4], c[4], b[4];
    float v[4];
#pragma unroll
    for (int i = 0; i < 4; ++i) {
        int e = base + tid + i * P1_THREADS;
        r[i] = row[e];
        c[i] = col[e];
        v[i] = vals[e];
        b[i] = r[i] / RSPAN;
        atomicAdd(&cnt[b[i]], 1);
    }
    __syncthreads();
    if (tid == 0) {
        int s = 0;
        for (int k = 0; k < NBKT; ++k) { lofs[k] = s; s += cnt[k]; }
        lofs[NBKT] = s;
    }
    __syncthreads();
    if (tid < NBKT) goff[tid] = atomicAdd(&bktCursor[tid], cnt[tid]);
    __syncthreads();
#pragma unroll
    for (int i = 0; i < 4; ++i) {
        int p = lofs[b[i]] + atomicAdd(&fill[b[i]], 1);
        rS[p] = r[i]; cS[p] = c[i]; vS[p] = v[i];
        bktS[p] = (unsigned char)b[i];
    }
    __syncthreads();
    for (int i = tid; i < P1_EDGES; i += P1_THREADS) {
        int bb = bktS[i];
        int g = goff[bb] + (i - lofs[bb]);
        rB[g] = rS[i]; cS[i] = cS[i];  // keep compiler from reordering oddly (no-op)
        cB[g] = cS[i]; vB[g] = vS[i];
    }
}

// Phase 2: scatter one bucket's edges to final CSR positions. Bucket chosen by
// (blockIdx & 7) so (under round-robin dispatch) all writers of a 2.4MB window
// live on one XCD -> partial lines merge in that XCD's L2.
__global__ void scatter2_kernel(const int* __restrict__ rB, const int* __restrict__ cB,
                                const float* __restrict__ vB, const int* __restrict__ rowPtr,
                                int* __restrict__ cursor, int2* __restrict__ edgeS,
                                int passBase) {
    int b = passBase + (blockIdx.x & 7);
    int sub = blockIdx.x >> 3;
    int s = rowPtr[b * RSPAN];
    int t = rowPtr[(b + 1) * RSPAN];
    for (int i = s + sub * 256 + threadIdx.x; i < t; i += P2_BPB * 256) {
        int r = rB[i];
        int pos = atomicAdd(&cursor[r], 1);
        edgeS[pos] = make_int2(cB[i], __float_as_int(vB[i]));
    }
}

// ---------------- SpMM ----------------
// 16 threads per node; each thread owns one float4 (4 of the 64 dims).

__global__ void spmm_l1(const int* __restrict__ rowPtr, const int2* __restrict__ edgeS,
                        const float4* __restrict__ ue, const float4* __restrict__ ie,
                        float4* __restrict__ y) {
    int lane = threadIdx.x & 15;
    int n = blockIdx.x * 16 + (threadIdx.x >> 4);
    int s = rowPtr[n], t = rowPtr[n + 1];
    float ax = 0.f, ay = 0.f, az = 0.f, aw = 0.f;
    for (int e = s; e < t; ++e) {
        int2 ev = edgeS[e];
        int c = ev.x;
        float v = __int_as_float(ev.y);
        float4 xv = (c < U) ? ue[(size_t)c * D4 + lane] : ie[(size_t)(c - U) * D4 + lane];
        ax = fmaf(v, xv.x, ax); ay = fmaf(v, xv.y, ay);
        az = fmaf(v, xv.z, az); aw = fmaf(v, xv.w, aw);
    }
    float4 o; o.x = ax; o.y = ay; o.z = az; o.w = aw;
    y[(size_t)n * D4 + lane] = o;
}

__global__ void spmm_mid(const int* __restrict__ rowPtr, const int2* __restrict__ edgeS,
                         const float4* __restrict__ x, float4* __restrict__ y) {
    int lane = threadIdx.x & 15;
    int n = blockIdx.x * 16 + (threadIdx.x >> 4);
    int s = rowPtr[n], t = rowPtr[n + 1];
    float ax = 0.f, ay = 0.f, az = 0.f, aw = 0.f;
    for (int e = s; e < t; ++e) {
        int2 ev = edgeS[e];
        int c = ev.x;
        float v = __int_as_float(ev.y);
        float4 xv = x[(size_t)c * D4 + lane];
        ax = fmaf(v, xv.x, ax); ay = fmaf(v, xv.y, ay);
        az = fmaf(v, xv.z, az); aw = fmaf(v, xv.w, aw);
    }
    float4 o; o.x = ax; o.y = ay; o.z = az; o.w = aw;
    y[(size_t)n * D4 + lane] = o;
}

// Layer-3 SpMM fused with the full output epilogue.
// out layout (float4 units): users[U*16] | items[I*16] | um0 um1 um2 (U*16 each) | im0 im1 im2 (I*16 each)
__global__ void spmm_final(const int* __restrict__ rowPtr, const int2* __restrict__ edgeS,
                           const float4* __restrict__ h2, const float4* __restrict__ h1,
                           const float4* __restrict__ ue, const float4* __restrict__ ie,
                           float4* __restrict__ out) {
    int lane = threadIdx.x & 15;
    int n = blockIdx.x * 16 + (threadIdx.x >> 4);
    int s = rowPtr[n], t = rowPtr[n + 1];
    float ax = 0.f, ay = 0.f, az = 0.f, aw = 0.f;
    for (int e = s; e < t; ++e) {
        int2 ev = edgeS[e];
        int c = ev.x;
        float v = __int_as_float(ev.y);
        float4 xv = h2[(size_t)c * D4 + lane];
        ax = fmaf(v, xv.x, ax); ay = fmaf(v, xv.y, ay);
        az = fmaf(v, xv.z, az); aw = fmaf(v, xv.w, aw);
    }
    size_t r16 = (size_t)n * D4 + lane;
    float4 e0 = (n < U) ? ue[r16] : ie[(size_t)(n - U) * D4 + lane];
    float4 a1 = h1[r16];
    float4 a2 = h2[r16];

    float c1x = e0.x + a1.x, c1y = e0.y + a1.y, c1z = e0.z + a1.z, c1w = e0.w + a1.w;
    float c2x = c1x + a2.x, c2y = c1y + a2.y, c2z = c1z + a2.z, c2w = c1w + a2.w;
    float c3x = c2x + ax,   c3y = c2y + ay,   c3z = c2z + az,   c3w = c2w + aw;

    float4 um0; um0.x = c1x * 0.5f; um0.y = c1y * 0.5f; um0.z = c1z * 0.5f; um0.w = c1w * 0.5f;
    float4 um1; um1.x = c2x / 3.0f; um1.y = c2y / 3.0f; um1.z = c2z / 3.0f; um1.w = c2w / 3.0f;
    float4 m;   m.x   = c3x * 0.25f; m.y  = c3y * 0.25f; m.z  = c3z * 0.25f; m.w  = c3w * 0.25f;

    constexpr size_t N16 = (size_t)N * D4;
    constexpr size_t U16 = (size_t)U * D4;
    constexpr size_t I16 = (size_t)I * D4;
    if (n < U) {
        size_t r = (size_t)n * D4 + lane;
        out[r] = m;                           // users
        out[N16 + r] = um0;                   // users_mean0
        out[N16 + U16 + r] = um1;             // users_mean1
        out[N16 + 2 * U16 + r] = m;           // users_mean2 == users
    } else {
        size_t r = (size_t)(n - U) * D4 + lane;
        out[U16 + r] = m;                     // items
        out[N16 + 3 * U16 + r] = um0;         // items_mean0
        out[N16 + 3 * U16 + I16 + r] = um1;   // items_mean1
        out[N16 + 3 * U16 + 2 * I16 + r] = m; // items_mean2 == items
    }
}

extern "C" void kernel_launch(void* const* d_in, const int* in_sizes, int n_in,
                              void* d_out, int out_size, void* d_ws, size_t ws_size,
                              hipStream_t stream) {
    const float* ue   = (const float*)d_in[0];
    const float* ie   = (const float*)d_in[1];
    const int*   row  = (const int*)d_in[2];
    const int*   col  = (const int*)d_in[3];
    const float* vals = (const float*)d_in[4];

    char* ws = (char*)d_ws;
    size_t off = 0;
    float* h1     = (float*)(ws + off); off += (size_t)N * 64 * 4;   // 76.8 MB
    float* h2     = (float*)(ws + off); off += (size_t)N * 64 * 4;   // 76.8 MB
    int2*  edgeS  = (int2*)(ws + off);  off += (size_t)E * 8;        // 76.8 MB
    int*   counts = (int*)(ws + off);   off += (size_t)(N + 1) * 4;  // counts, then cursor
    int*   rowPtr = (int*)(ws + off);   off += (size_t)(N + 1) * 4;
    int*   bsums  = (int*)(ws + off);   off += 4096;
    int*   bktCur = (int*)(ws + off);   off += 256;
    // Phase-1 bucket arenas alias h1/h2 (fully consumed before spmm writes them).
    int*   rB = (int*)h1;                      // 38.4 MB
    int*   cB = (int*)((char*)h1 + (size_t)E * 4);
    float* vB = (float*)h2;                    // 38.4 MB

    // ---- CSR build (deterministic work, rebuilt every call) ----
    hipMemsetAsync(counts, 0, (size_t)(N + 1) * 4, stream);
    hist_kernel<<<(E + 255) / 256, 256, 0, stream>>>(row, counts, E);
    const int nScan = N + 1;
    const int nB = (nScan + SCAN_CHUNK - 1) / SCAN_CHUNK;   // 293
    scan_phase1<<<nB, SCAN_BLOCK, 0, stream>>>(counts, rowPtr, bsums, nScan);
    scan_phase1<<<1, SCAN_BLOCK, 0, stream>>>(bsums, bsums, nullptr, nB);
    scan_phase3<<<nB, SCAN_BLOCK, 0, stream>>>(rowPtr, bsums, nScan);
    init_bkt<<<1, 64, 0, stream>>>(rowPtr, bktCur);
    hipMemcpyAsync(counts, rowPtr, (size_t)N * 4, hipMemcpyDeviceToDevice, stream); // cursor

    // Phase 1: coarse bucket (coalesced writes).
    bucket_kernel<<<E / P1_EDGES, P1_THREADS, 0, stream>>>(row, col, vals, bktCur, rB, cB, vB);
    // Phase 2: windowed scatter, 4 passes x 8 XCD-mapped buckets.
    for (int pass = 0; pass < 4; ++pass) {
        scatter2_kernel<<<8 * P2_BPB, 256, 0, stream>>>(rB, cB, vB, rowPtr, counts, edgeS,
                                                        pass * 8);
    }

    // ---- 3 SpMM layers (layer 3 fused with output epilogue) ----
    const int spmmBlocks = N / 16;  // 18750, 16 nodes per 256-thread block
    spmm_l1<<<spmmBlocks, 256, 0, stream>>>(rowPtr, edgeS,
                                            (const float4*)ue, (const float4*)ie, (float4*)h1);
    spmm_mid<<<spmmBlocks, 256, 0, stream>>>(rowPtr, edgeS, (const float4*)h1, (float4*)h2);
    spmm_final<<<spmmBlocks, 256, 0, stream>>>(rowPtr, edgeS,
                                               (const float4*)h2, (const float4*)h1,
                                               (const float4*)ue, (const float4*)ie,
                                               (float4*)d_out);
}

// Round 3
// 1864.432 us; speedup vs baseline: 1.1746x; 1.1119x over previous
//
#include <hip/hip_runtime.h>

// Problem constants (fixed by the reference).
constexpr int U = 200000;
constexpr int I = 100000;
constexpr int N = 300000;   // U + I
constexpr int E = 9600000;
constexpr int D4 = 16;      // D=64 floats -> 16 float4 per row (f32 paths)

constexpr int SCAN_BLOCK = 256;
constexpr int SCAN_ITEMS = 4;
constexpr int SCAN_CHUNK = SCAN_BLOCK * SCAN_ITEMS;  // 1024

constexpr int NBKT = 32;            // coarse row-range buckets
constexpr int RSPAN = N / NBKT;     // 9375 rows per bucket -> 2.4MB edgeS window (fits 4MB XCD L2)
constexpr int P1_EDGES = 1024;      // edges staged per block in phase 1
constexpr int P1_THREADS = 256;
constexpr int P2_BPB = 256;         // blocks per bucket in phase 2

__device__ __forceinline__ float bf2f(unsigned short u) {
    return __uint_as_float(((unsigned int)u) << 16);
}
__device__ __forceinline__ unsigned short f2bf(float f) {
    unsigned int u = __float_as_uint(f);
    unsigned int r = (u + 0x7fffu + ((u >> 16) & 1u)) >> 16;  // RNE
    return (unsigned short)r;
}

// ---------------- CSR build ----------------

__global__ void hist_kernel(const int* __restrict__ row, int* __restrict__ counts, int e_cnt) {
    int e = blockIdx.x * blockDim.x + threadIdx.x;
    if (e < e_cnt) atomicAdd(&counts[row[e]], 1);
}

// Exclusive scan, phase 1: per-block scan + block totals.
// Also reused (grid=1, blockSums=nullptr) as the phase-2 scan of block totals.
__global__ void scan_phase1(const int* __restrict__ in, int* __restrict__ out,
                            int* __restrict__ blockSums, int n) {
    __shared__ int sdata[SCAN_BLOCK];
    int tid = threadIdx.x;
    int base = blockIdx.x * SCAN_CHUNK + tid * SCAN_ITEMS;
    int pref[SCAN_ITEMS];
    int sum = 0;
#pragma unroll
    for (int i = 0; i < SCAN_ITEMS; ++i) {
        int idx = base + i;
        int v = (idx < n) ? in[idx] : 0;
        pref[i] = sum;
        sum += v;
    }
    sdata[tid] = sum;
    __syncthreads();
    for (int off = 1; off < SCAN_BLOCK; off <<= 1) {
        int t = (tid >= off) ? sdata[tid - off] : 0;
        __syncthreads();
        sdata[tid] += t;
        __syncthreads();
    }
    int texcl = (tid == 0) ? 0 : sdata[tid - 1];
    if (tid == SCAN_BLOCK - 1 && blockSums) blockSums[blockIdx.x] = sdata[SCAN_BLOCK - 1];
#pragma unroll
    for (int i = 0; i < SCAN_ITEMS; ++i) {
        int idx = base + i;
        if (idx < n) out[idx] = texcl + pref[i];
    }
}

__global__ void scan_phase3(int* __restrict__ out, const int* __restrict__ blockSums, int n) {
    int base = blockIdx.x * SCAN_CHUNK + threadIdx.x * SCAN_ITEMS;
    int add = blockSums[blockIdx.x];
#pragma unroll
    for (int i = 0; i < SCAN_ITEMS; ++i) {
        int idx = base + i;
        if (idx < n) out[idx] += add;
    }
}

__global__ void init_bkt(const int* __restrict__ rowPtr, int* __restrict__ bktCursor) {
    int t = threadIdx.x;
    if (t < NBKT) bktCursor[t] = rowPtr[t * RSPAN];
}

// Phase 1: LDS multisplit into 32 row-range buckets (coalesced per-bucket
// segment writes -> no write amplification).
__global__ void bucket_kernel(const int* __restrict__ row, const int* __restrict__ col,
                              const float* __restrict__ vals, int* __restrict__ bktCursor,
                              int* __restrict__ rB, int* __restrict__ cB, float* __restrict__ vB) {
    __shared__ int cnt[NBKT];
    __shared__ int fill[NBKT];
    __shared__ int lofs[NBKT + 1];
    __shared__ int goff[NBKT];
    __shared__ int rS[P1_EDGES];
    __shared__ int cS[P1_EDGES];
    __shared__ float vS[P1_EDGES];
    __shared__ unsigned char bktS[P1_EDGES];

    int tid = threadIdx.x;
    int base = blockIdx.x * P1_EDGES;
    if (tid < NBKT) { cnt[tid] = 0; fill[tid] = 0; }
    __syncthreads();

    int r[4], c[4], b[4];
    float v[4];
#pragma unroll
    for (int i = 0; i < 4; ++i) {
        int e = base + tid + i * P1_THREADS;
        r[i] = row[e];
        c[i] = col[e];
        v[i] = vals[e];
        b[i] = r[i] / RSPAN;
        atomicAdd(&cnt[b[i]], 1);
    }
    __syncthreads();
    if (tid == 0) {
        int s = 0;
        for (int k = 0; k < NBKT; ++k) { lofs[k] = s; s += cnt[k]; }
        lofs[NBKT] = s;
    }
    __syncthreads();
    if (tid < NBKT) goff[tid] = atomicAdd(&bktCursor[tid], cnt[tid]);
    __syncthreads();
#pragma unroll
    for (int i = 0; i < 4; ++i) {
        int p = lofs[b[i]] + atomicAdd(&fill[b[i]], 1);
        rS[p] = r[i]; cS[p] = c[i]; vS[p] = v[i];
        bktS[p] = (unsigned char)b[i];
    }
    __syncthreads();
    for (int i = tid; i < P1_EDGES; i += P1_THREADS) {
        int bb = bktS[i];
        int g = goff[bb] + (i - lofs[bb]);
        rB[g] = rS[i];
        cB[g] = cS[i];
        vB[g] = vS[i];
    }
}

// Phase 2: scatter one bucket's edges to final CSR positions; bucket via
// (blockIdx & 7) keeps each 2.4MB destination window XCD-local (L2 merges lines).
__global__ void scatter2_kernel(const int* __restrict__ rB, const int* __restrict__ cB,
                                const float* __restrict__ vB, const int* __restrict__ rowPtr,
                                int* __restrict__ cursor, int2* __restrict__ edgeS,
                                int passBase) {
    int b = passBase + (blockIdx.x & 7);
    int sub = blockIdx.x >> 3;
    int s = rowPtr[b * RSPAN];
    int t = rowPtr[(b + 1) * RSPAN];
    for (int i = s + sub * 256 + threadIdx.x; i < t; i += P2_BPB * 256) {
        int r = rB[i];
        int pos = atomicAdd(&cursor[r], 1);
        edgeS[pos] = make_int2(cB[i], __float_as_int(vB[i]));
    }
}

// ---------------- bf16 conversion ----------------
// e0b[n] = bf16(concat(ue,ie)[n]); one thread per 4 elements.
__global__ void conv_e0(const float4* __restrict__ ue, const float4* __restrict__ ie,
                        ushort4* __restrict__ e0b) {
    size_t i = (size_t)blockIdx.x * blockDim.x + threadIdx.x;  // float4 index
    constexpr size_t U16 = (size_t)U * D4;
    constexpr size_t N16 = (size_t)N * D4;
    if (i >= N16) return;
    float4 f = (i < U16) ? ue[i] : ie[i - U16];
    ushort4 o;
    o.x = f2bf(f.x); o.y = f2bf(f.y); o.z = f2bf(f.z); o.w = f2bf(f.w);
    e0b[i] = o;
}

// ---------------- SpMM (bf16 gather, f32 accumulate) ----------------
// 16 threads per node; each thread owns 4 dims (ushort4 = 8B; 16 lanes = one
// 128B L2 line per gathered row).

__global__ void spmm_b(const int* __restrict__ rowPtr, const int2* __restrict__ edgeS,
                       const ushort4* __restrict__ xb, ushort4* __restrict__ yb) {
    int lane = threadIdx.x & 15;
    int n = blockIdx.x * 16 + (threadIdx.x >> 4);
    int s = rowPtr[n], t = rowPtr[n + 1];
    float ax = 0.f, ay = 0.f, az = 0.f, aw = 0.f;
    for (int e = s; e < t; ++e) {
        int2 ev = edgeS[e];
        float v = __int_as_float(ev.y);
        ushort4 xv = xb[(size_t)ev.x * D4 + lane];
        ax = fmaf(v, bf2f(xv.x), ax); ay = fmaf(v, bf2f(xv.y), ay);
        az = fmaf(v, bf2f(xv.z), az); aw = fmaf(v, bf2f(xv.w), aw);
    }
    ushort4 o;
    o.x = f2bf(ax); o.y = f2bf(ay); o.z = f2bf(az); o.w = f2bf(aw);
    yb[(size_t)n * D4 + lane] = o;
}

// Layer-3 SpMM fused with the full output epilogue (f32 outputs).
// out layout (float4 units): users[U*16] | items[I*16] | um0 um1 um2 (U*16 each) | im0 im1 im2 (I*16 each)
__global__ void spmm_final(const int* __restrict__ rowPtr, const int2* __restrict__ edgeS,
                           const ushort4* __restrict__ h2b, const ushort4* __restrict__ h1b,
                           const float4* __restrict__ ue, const float4* __restrict__ ie,
                           float4* __restrict__ out) {
    int lane = threadIdx.x & 15;
    int n = blockIdx.x * 16 + (threadIdx.x >> 4);
    int s = rowPtr[n], t = rowPtr[n + 1];
    float ax = 0.f, ay = 0.f, az = 0.f, aw = 0.f;
    for (int e = s; e < t; ++e) {
        int2 ev = edgeS[e];
        float v = __int_as_float(ev.y);
        ushort4 xv = h2b[(size_t)ev.x * D4 + lane];
        ax = fmaf(v, bf2f(xv.x), ax); ay = fmaf(v, bf2f(xv.y), ay);
        az = fmaf(v, bf2f(xv.z), az); aw = fmaf(v, bf2f(xv.w), aw);
    }
    size_t r16 = (size_t)n * D4 + lane;
    float4 e0 = (n < U) ? ue[r16] : ie[(size_t)(n - U) * D4 + lane];
    ushort4 b1 = h1b[r16];
    ushort4 b2 = h2b[r16];

    float c1x = e0.x + bf2f(b1.x), c1y = e0.y + bf2f(b1.y);
    float c1z = e0.z + bf2f(b1.z), c1w = e0.w + bf2f(b1.w);
    float c2x = c1x + bf2f(b2.x), c2y = c1y + bf2f(b2.y);
    float c2z = c1z + bf2f(b2.z), c2w = c1w + bf2f(b2.w);
    float c3x = c2x + ax, c3y = c2y + ay, c3z = c2z + az, c3w = c2w + aw;

    float4 um0; um0.x = c1x * 0.5f;  um0.y = c1y * 0.5f;  um0.z = c1z * 0.5f;  um0.w = c1w * 0.5f;
    float4 um1; um1.x = c2x / 3.0f;  um1.y = c2y / 3.0f;  um1.z = c2z / 3.0f;  um1.w = c2w / 3.0f;
    float4 m;   m.x   = c3x * 0.25f; m.y   = c3y * 0.25f; m.z   = c3z * 0.25f; m.w   = c3w * 0.25f;

    constexpr size_t N16 = (size_t)N * D4;
    constexpr size_t U16 = (size_t)U * D4;
    constexpr size_t I16 = (size_t)I * D4;
    if (n < U) {
        size_t r = (size_t)n * D4 + lane;
        out[r] = m;                           // users
        out[N16 + r] = um0;                   // users_mean0
        out[N16 + U16 + r] = um1;             // users_mean1
        out[N16 + 2 * U16 + r] = m;           // users_mean2 == users
    } else {
        size_t r = (size_t)(n - U) * D4 + lane;
        out[U16 + r] = m;                     // items
        out[N16 + 3 * U16 + r] = um0;         // items_mean0
        out[N16 + 3 * U16 + I16 + r] = um1;   // items_mean1
        out[N16 + 3 * U16 + 2 * I16 + r] = m; // items_mean2 == items
    }
}

extern "C" void kernel_launch(void* const* d_in, const int* in_sizes, int n_in,
                              void* d_out, int out_size, void* d_ws, size_t ws_size,
                              hipStream_t stream) {
    const float* ue   = (const float*)d_in[0];
    const float* ie   = (const float*)d_in[1];
    const int*   row  = (const int*)d_in[2];
    const int*   col  = (const int*)d_in[3];
    const float* vals = (const float*)d_in[4];

    char* ws = (char*)d_ws;
    size_t off = 0;
    // blob0: 115.2MB. First life: bucket arenas rB|cB|vB. Second life: e0b|h1b|h2b.
    char* blob0 = ws + off; off += (size_t)3 * E * 4;
    int2* edgeS  = (int2*)(ws + off); off += (size_t)E * 8;          // 76.8 MB
    int*  counts = (int*)(ws + off);  off += (size_t)(N + 1) * 4;    // counts, then cursor
    int*  rowPtr = (int*)(ws + off);  off += (size_t)(N + 1) * 4;
    int*  bsums  = (int*)(ws + off);  off += 4096;
    int*  bktCur = (int*)(ws + off);  off += 256;

    int*     rB  = (int*)blob0;
    int*     cB  = (int*)(blob0 + (size_t)E * 4);
    float*   vB  = (float*)(blob0 + (size_t)2 * E * 4);
    ushort4* e0b = (ushort4*)blob0;                        // N*64 bf16 = 38.4MB
    ushort4* h1b = (ushort4*)(blob0 + (size_t)E * 4);
    ushort4* h2b = (ushort4*)(blob0 + (size_t)2 * E * 4);

    // ---- CSR build (rebuilt every call; deterministic work) ----
    hipMemsetAsync(counts, 0, (size_t)(N + 1) * 4, stream);
    hist_kernel<<<(E + 255) / 256, 256, 0, stream>>>(row, counts, E);
    const int nScan = N + 1;
    const int nB = (nScan + SCAN_CHUNK - 1) / SCAN_CHUNK;   // 293
    scan_phase1<<<nB, SCAN_BLOCK, 0, stream>>>(counts, rowPtr, bsums, nScan);
    scan_phase1<<<1, SCAN_BLOCK, 0, stream>>>(bsums, bsums, nullptr, nB);
    scan_phase3<<<nB, SCAN_BLOCK, 0, stream>>>(rowPtr, bsums, nScan);
    init_bkt<<<1, 64, 0, stream>>>(rowPtr, bktCur);
    hipMemcpyAsync(counts, rowPtr, (size_t)N * 4, hipMemcpyDeviceToDevice, stream); // cursor

    bucket_kernel<<<E / P1_EDGES, P1_THREADS, 0, stream>>>(row, col, vals, bktCur, rB, cB, vB);
    for (int pass = 0; pass < 4; ++pass) {
        scatter2_kernel<<<8 * P2_BPB, 256, 0, stream>>>(rB, cB, vB, rowPtr, counts, edgeS,
                                                        pass * 8);
    }

    // ---- bf16 e0 (arenas are dead now; blob0 becomes e0b|h1b|h2b) ----
    const size_t n16 = (size_t)N * D4;
    conv_e0<<<(int)((n16 + 255) / 256), 256, 0, stream>>>((const float4*)ue, (const float4*)ie,
                                                          e0b);

    // ---- 3 SpMM layers (layer 3 fused with output epilogue) ----
    const int spmmBlocks = N / 16;  // 18750, 16 nodes per 256-thread block
    spmm_b<<<spmmBlocks, 256, 0, stream>>>(rowPtr, edgeS, e0b, h1b);
    spmm_b<<<spmmBlocks, 256, 0, stream>>>(rowPtr, edgeS, h1b, h2b);
    spmm_final<<<spmmBlocks, 256, 0, stream>>>(rowPtr, edgeS, h2b, h1b,
                                               (const float4*)ue, (const float4*)ie,
                                               (float4*)d_out);
}

// Round 4
// 1533.943 us; speedup vs baseline: 1.4277x; 1.2155x over previous
//
#include <hip/hip_runtime.h>

// Problem constants (fixed by the reference).
constexpr int U = 200000;
constexpr int I = 100000;
constexpr int N = 300000;   // U + I
constexpr int E = 9600000;
constexpr int D4 = 16;      // D=64 floats -> 16 float4 per row (f32 paths)

constexpr int SCAN_BLOCK = 256;
constexpr int SCAN_ITEMS = 4;
constexpr int SCAN_CHUNK = SCAN_BLOCK * SCAN_ITEMS;  // 1024

constexpr int NBKT = 32;            // coarse row-range buckets
constexpr int RSPAN = N / NBKT;     // 9375 rows per bucket
constexpr int ARENA_CAP = 310000;   // fixed arena capacity (mean 300K, sigma~550 -> 18 sigma slack)
constexpr int P1_EDGES = 1024;      // edges staged per block in phase 1
constexpr int P1_THREADS = 256;
constexpr int P2_BPB = 256;         // blocks per bucket in phase 2
constexpr int HB = 16;              // hist blocks per bucket

__device__ __forceinline__ float bf2f(unsigned short u) {
    return __uint_as_float(((unsigned int)u) << 16);
}
__device__ __forceinline__ unsigned short f2bf(float f) {
    unsigned int u = __float_as_uint(f);
    unsigned int r = (u + 0x7fffu + ((u >> 16) & 1u)) >> 16;  // RNE
    return (unsigned short)r;
}

// ---------------- CSR build ----------------

__global__ void init_bkt(int* __restrict__ bktCursor) {
    int t = threadIdx.x;
    if (t < NBKT) bktCursor[t] = t * ARENA_CAP;
}

// Phase 1: LDS multisplit into 32 fixed-capacity row-range bucket arenas
// (coalesced per-bucket segment writes -> no write amplification).
__global__ void bucket_kernel(const int* __restrict__ row, const int* __restrict__ col,
                              const float* __restrict__ vals, int* __restrict__ bktCursor,
                              int* __restrict__ rB, int* __restrict__ cB, float* __restrict__ vB) {
    __shared__ int cnt[NBKT];
    __shared__ int fill[NBKT];
    __shared__ int lofs[NBKT + 1];
    __shared__ int goff[NBKT];
    __shared__ int rS[P1_EDGES];
    __shared__ int cS[P1_EDGES];
    __shared__ float vS[P1_EDGES];
    __shared__ unsigned char bktS[P1_EDGES];

    int tid = threadIdx.x;
    int base = blockIdx.x * P1_EDGES;
    if (tid < NBKT) { cnt[tid] = 0; fill[tid] = 0; }
    __syncthreads();

    int r[4], c[4], b[4];
    float v[4];
#pragma unroll
    for (int i = 0; i < 4; ++i) {
        int e = base + tid + i * P1_THREADS;
        r[i] = row[e];
        c[i] = col[e];
        v[i] = vals[e];
        b[i] = r[i] / RSPAN;
        atomicAdd(&cnt[b[i]], 1);
    }
    __syncthreads();
    if (tid == 0) {
        int s = 0;
        for (int k = 0; k < NBKT; ++k) { lofs[k] = s; s += cnt[k]; }
        lofs[NBKT] = s;
    }
    __syncthreads();
    if (tid < NBKT) goff[tid] = atomicAdd(&bktCursor[tid], cnt[tid]);
    __syncthreads();
#pragma unroll
    for (int i = 0; i < 4; ++i) {
        int p = lofs[b[i]] + atomicAdd(&fill[b[i]], 1);
        rS[p] = r[i]; cS[p] = c[i]; vS[p] = v[i];
        bktS[p] = (unsigned char)b[i];
    }
    __syncthreads();
    for (int i = tid; i < P1_EDGES; i += P1_THREADS) {
        int bb = bktS[i];
        int g = goff[bb] + (i - lofs[bb]);
        rB[g] = rS[i];
        cB[g] = cS[i];
        vB[g] = vS[i];
    }
}

// Histogram from bucket arenas: 9375 LDS counters per block (37.5KB), then a
// coalesced contiguous atomic flush. No random device atomics.
__global__ void hist2_kernel(const int* __restrict__ rB, const int* __restrict__ bktCur,
                             int* __restrict__ counts) {
    __shared__ int lcnt[RSPAN];
    int b = blockIdx.x & (NBKT - 1);
    int sub = blockIdx.x >> 5;
    int tid = threadIdx.x;
    for (int i = tid; i < RSPAN; i += 256) lcnt[i] = 0;
    __syncthreads();
    int s = b * ARENA_CAP;
    int t = bktCur[b];
    int rbase = b * RSPAN;
    for (int i = s + sub * 256 + tid; i < t; i += HB * 256) {
        atomicAdd(&lcnt[rB[i] - rbase], 1);
    }
    __syncthreads();
    for (int i = tid; i < RSPAN; i += 256) {
        int c = lcnt[i];
        if (c) atomicAdd(&counts[rbase + i], c);
    }
}

// Exclusive scan, phase 1: per-block scan + block totals.
// Also reused (grid=1, blockSums=nullptr) as the phase-2 scan of block totals.
__global__ void scan_phase1(const int* __restrict__ in, int* __restrict__ out,
                            int* __restrict__ blockSums, int n) {
    __shared__ int sdata[SCAN_BLOCK];
    int tid = threadIdx.x;
    int base = blockIdx.x * SCAN_CHUNK + tid * SCAN_ITEMS;
    int pref[SCAN_ITEMS];
    int sum = 0;
#pragma unroll
    for (int i = 0; i < SCAN_ITEMS; ++i) {
        int idx = base + i;
        int v = (idx < n) ? in[idx] : 0;
        pref[i] = sum;
        sum += v;
    }
    sdata[tid] = sum;
    __syncthreads();
    for (int off = 1; off < SCAN_BLOCK; off <<= 1) {
        int t = (tid >= off) ? sdata[tid - off] : 0;
        __syncthreads();
        sdata[tid] += t;
        __syncthreads();
    }
    int texcl = (tid == 0) ? 0 : sdata[tid - 1];
    if (tid == SCAN_BLOCK - 1 && blockSums) blockSums[blockIdx.x] = sdata[SCAN_BLOCK - 1];
#pragma unroll
    for (int i = 0; i < SCAN_ITEMS; ++i) {
        int idx = base + i;
        if (idx < n) out[idx] = texcl + pref[i];
    }
}

__global__ void scan_phase3(int* __restrict__ out, const int* __restrict__ blockSums, int n) {
    int base = blockIdx.x * SCAN_CHUNK + threadIdx.x * SCAN_ITEMS;
    int add = blockSums[blockIdx.x];
#pragma unroll
    for (int i = 0; i < SCAN_ITEMS; ++i) {
        int idx = base + i;
        if (idx < n) out[idx] += add;
    }
}

// Phase 2: scatter one bucket's edges to final CSR positions; bucket via
// (blockIdx & 7) keeps each 2.4MB destination window XCD-local (L2 merges lines).
__global__ void scatter2_kernel(const int* __restrict__ rB, const int* __restrict__ cB,
                                const float* __restrict__ vB, const int* __restrict__ bktCur,
                                int* __restrict__ cursor, int2* __restrict__ edgeS,
                                int passBase) {
    int b = passBase + (blockIdx.x & 7);
    int sub = blockIdx.x >> 3;
    int s = b * ARENA_CAP;
    int t = bktCur[b];
    for (int i = s + sub * 256 + threadIdx.x; i < t; i += P2_BPB * 256) {
        int r = rB[i];
        int pos = atomicAdd(&cursor[r], 1);
        edgeS[pos] = make_int2(cB[i], __float_as_int(vB[i]));
    }
}

// ---------------- bf16 conversion ----------------
__global__ void conv_e0(const float4* __restrict__ ue, const float4* __restrict__ ie,
                        ushort4* __restrict__ e0b) {
    size_t i = (size_t)blockIdx.x * blockDim.x + threadIdx.x;  // float4 index
    constexpr size_t U16 = (size_t)U * D4;
    constexpr size_t N16 = (size_t)N * D4;
    if (i >= N16) return;
    float4 f = (i < U16) ? ue[i] : ie[i - U16];
    ushort4 o;
    o.x = f2bf(f.x); o.y = f2bf(f.y); o.z = f2bf(f.z); o.w = f2bf(f.w);
    e0b[i] = o;
}

// ---------------- SpMM (bf16 gather, f32 accumulate) ----------------
// 16 threads per node; each thread owns 4 dims (ushort4 = 8B; 16 lanes = one
// 128B L2 line per gathered row).

__global__ void spmm_b(const int* __restrict__ rowPtr, const int2* __restrict__ edgeS,
                       const ushort4* __restrict__ xb, ushort4* __restrict__ yb) {
    int lane = threadIdx.x & 15;
    int n = blockIdx.x * 16 + (threadIdx.x >> 4);
    int s = rowPtr[n], t = rowPtr[n + 1];
    float ax = 0.f, ay = 0.f, az = 0.f, aw = 0.f;
    for (int e = s; e < t; ++e) {
        int2 ev = edgeS[e];
        float v = __int_as_float(ev.y);
        ushort4 xv = xb[(size_t)ev.x * D4 + lane];
        ax = fmaf(v, bf2f(xv.x), ax); ay = fmaf(v, bf2f(xv.y), ay);
        az = fmaf(v, bf2f(xv.z), az); aw = fmaf(v, bf2f(xv.w), aw);
    }
    ushort4 o;
    o.x = f2bf(ax); o.y = f2bf(ay); o.z = f2bf(az); o.w = f2bf(aw);
    yb[(size_t)n * D4 + lane] = o;
}

// Layer-3 SpMM fused with the full output epilogue (f32 outputs).
// out layout (float4 units): users[U*16] | items[I*16] | um0 um1 um2 (U*16 each) | im0 im1 im2 (I*16 each)
__global__ void spmm_final(const int* __restrict__ rowPtr, const int2* __restrict__ edgeS,
                           const ushort4* __restrict__ h2b, const ushort4* __restrict__ h1b,
                           const float4* __restrict__ ue, const float4* __restrict__ ie,
                           float4* __restrict__ out) {
    int lane = threadIdx.x & 15;
    int n = blockIdx.x * 16 + (threadIdx.x >> 4);
    int s = rowPtr[n], t = rowPtr[n + 1];
    float ax = 0.f, ay = 0.f, az = 0.f, aw = 0.f;
    for (int e = s; e < t; ++e) {
        int2 ev = edgeS[e];
        float v = __int_as_float(ev.y);
        ushort4 xv = h2b[(size_t)ev.x * D4 + lane];
        ax = fmaf(v, bf2f(xv.x), ax); ay = fmaf(v, bf2f(xv.y), ay);
        az = fmaf(v, bf2f(xv.z), az); aw = fmaf(v, bf2f(xv.w), aw);
    }
    size_t r16 = (size_t)n * D4 + lane;
    float4 e0 = (n < U) ? ue[r16] : ie[(size_t)(n - U) * D4 + lane];
    ushort4 b1 = h1b[r16];
    ushort4 b2 = h2b[r16];

    float c1x = e0.x + bf2f(b1.x), c1y = e0.y + bf2f(b1.y);
    float c1z = e0.z + bf2f(b1.z), c1w = e0.w + bf2f(b1.w);
    float c2x = c1x + bf2f(b2.x), c2y = c1y + bf2f(b2.y);
    float c2z = c1z + bf2f(b2.z), c2w = c1w + bf2f(b2.w);
    float c3x = c2x + ax, c3y = c2y + ay, c3z = c2z + az, c3w = c2w + aw;

    float4 um0; um0.x = c1x * 0.5f;  um0.y = c1y * 0.5f;  um0.z = c1z * 0.5f;  um0.w = c1w * 0.5f;
    float4 um1; um1.x = c2x / 3.0f;  um1.y = c2y / 3.0f;  um1.z = c2z / 3.0f;  um1.w = c2w / 3.0f;
    float4 m;   m.x   = c3x * 0.25f; m.y   = c3y * 0.25f; m.z   = c3z * 0.25f; m.w   = c3w * 0.25f;

    constexpr size_t N16 = (size_t)N * D4;
    constexpr size_t U16 = (size_t)U * D4;
    constexpr size_t I16 = (size_t)I * D4;
    if (n < U) {
        size_t r = (size_t)n * D4 + lane;
        out[r] = m;                           // users
        out[N16 + r] = um0;                   // users_mean0
        out[N16 + U16 + r] = um1;             // users_mean1
        out[N16 + 2 * U16 + r] = m;           // users_mean2 == users
    } else {
        size_t r = (size_t)(n - U) * D4 + lane;
        out[U16 + r] = m;                     // items
        out[N16 + 3 * U16 + r] = um0;         // items_mean0
        out[N16 + 3 * U16 + I16 + r] = um1;   // items_mean1
        out[N16 + 3 * U16 + 2 * I16 + r] = m; // items_mean2 == items
    }
}

extern "C" void kernel_launch(void* const* d_in, const int* in_sizes, int n_in,
                              void* d_out, int out_size, void* d_ws, size_t ws_size,
                              hipStream_t stream) {
    const float* ue   = (const float*)d_in[0];
    const float* ie   = (const float*)d_in[1];
    const int*   row  = (const int*)d_in[2];
    const int*   col  = (const int*)d_in[3];
    const float* vals = (const float*)d_in[4];

    char* ws = (char*)d_ws;
    size_t off = 0;
    // blob0: 119MB arenas (rB|cB|vB, CAP-sized). Second life: e0b|h1b|h2b (38.4MB each).
    constexpr size_t ARENA_TOTAL = (size_t)NBKT * ARENA_CAP;   // 9.92M entries
    char* blob0 = ws + off; off += (size_t)3 * ARENA_TOTAL * 4;
    int2* edgeS  = (int2*)(ws + off); off += (size_t)E * 8;          // 76.8 MB
    int*  counts = (int*)(ws + off);  off += (size_t)(N + 1) * 4;    // counts, then cursor
    int*  rowPtr = (int*)(ws + off);  off += (size_t)(N + 1) * 4;
    int*  bsums  = (int*)(ws + off);  off += 4096;
    int*  bktCur = (int*)(ws + off);  off += 256;

    int*     rB  = (int*)blob0;
    int*     cB  = (int*)(blob0 + (size_t)ARENA_TOTAL * 4);
    float*   vB  = (float*)(blob0 + (size_t)2 * ARENA_TOTAL * 4);
    ushort4* e0b = (ushort4*)blob0;                        // N*64 bf16 = 38.4MB
    ushort4* h1b = (ushort4*)(blob0 + (size_t)E * 4);
    ushort4* h2b = (ushort4*)(blob0 + (size_t)2 * E * 4);

    // ---- CSR build (rebuilt every call; deterministic work) ----
    hipMemsetAsync(counts, 0, (size_t)(N + 1) * 4, stream);
    init_bkt<<<1, 64, 0, stream>>>(bktCur);
    bucket_kernel<<<E / P1_EDGES, P1_THREADS, 0, stream>>>(row, col, vals, bktCur, rB, cB, vB);
    hist2_kernel<<<NBKT * HB, 256, 0, stream>>>(rB, bktCur, counts);
    const int nScan = N + 1;
    const int nB = (nScan + SCAN_CHUNK - 1) / SCAN_CHUNK;   // 293
    scan_phase1<<<nB, SCAN_BLOCK, 0, stream>>>(counts, rowPtr, bsums, nScan);
    scan_phase1<<<1, SCAN_BLOCK, 0, stream>>>(bsums, bsums, nullptr, nB);
    scan_phase3<<<nB, SCAN_BLOCK, 0, stream>>>(rowPtr, bsums, nScan);
    hipMemcpyAsync(counts, rowPtr, (size_t)N * 4, hipMemcpyDeviceToDevice, stream); // cursor

    for (int pass = 0; pass < 4; ++pass) {
        scatter2_kernel<<<8 * P2_BPB, 256, 0, stream>>>(rB, cB, vB, bktCur, counts, edgeS,
                                                        pass * 8);
    }

    // ---- bf16 e0 (arenas rB dead after scatter; e0b aliases rB region) ----
    const size_t n16 = (size_t)N * D4;
    conv_e0<<<(int)((n16 + 255) / 256), 256, 0, stream>>>((const float4*)ue, (const float4*)ie,
                                                          e0b);

    // ---- 3 SpMM layers (layer 3 fused with output epilogue) ----
    const int spmmBlocks = N / 16;  // 18750, 16 nodes per 256-thread block
    spmm_b<<<spmmBlocks, 256, 0, stream>>>(rowPtr, edgeS, e0b, h1b);
    spmm_b<<<spmmBlocks, 256, 0, stream>>>(rowPtr, edgeS, h1b, h2b);
    spmm_final<<<spmmBlocks, 256, 0, stream>>>(rowPtr, edgeS, h2b, h1b,
                                               (const float4*)ue, (const float4*)ie,
                                               (float4*)d_out);
}

// Round 6
// 1290.937 us; speedup vs baseline: 1.6965x; 1.1882x over previous
//
#include <hip/hip_runtime.h>

// Problem constants (fixed by the reference).
constexpr int U = 200000;
constexpr int I = 100000;
constexpr int N = 300000;   // U + I
constexpr int E = 9600000;
constexpr int D4 = 16;      // D=64 floats -> 16 float4 per row (f32 paths)
constexpr int D8 = 8;       // D=64 bf16 -> 8 uint4 (16B) per row

constexpr int SCAN_BLOCK = 256;
constexpr int SCAN_ITEMS = 4;
constexpr int SCAN_CHUNK = SCAN_BLOCK * SCAN_ITEMS;  // 1024

constexpr int NBKT = 32;            // coarse row-range buckets
constexpr int RSPAN = N / NBKT;     // 9375 rows per bucket
constexpr int ARENA_CAP = 310000;   // fixed arena capacity (mean 300K, ~18 sigma slack)
constexpr int P1_EDGES = 1024;      // edges staged per block in phase 1
constexpr int P1_THREADS = 256;
constexpr int P2_BPB = 256;         // blocks per bucket in phase 2
constexpr int HB = 16;              // hist blocks per bucket

typedef float f32x4 __attribute__((ext_vector_type(4)));  // native vector for nontemporal stores

__device__ __forceinline__ void nt_store4(float4 v, float4* p) {
    f32x4 w = {v.x, v.y, v.z, v.w};
    __builtin_nontemporal_store(w, (f32x4*)p);
}

__device__ __forceinline__ unsigned short f2bf(float f) {
    unsigned int u = __float_as_uint(f);
    unsigned int r = (u + 0x7fffu + ((u >> 16) & 1u)) >> 16;  // RNE
    return (unsigned short)r;
}
__device__ __forceinline__ unsigned int packbf(float lo, float hi) {
    return (unsigned int)f2bf(lo) | ((unsigned int)f2bf(hi) << 16);
}

// a[2k] += v*lo(u[k]); a[2k+1] += v*hi(u[k])  (8 packed bf16 in a uint4)
__device__ __forceinline__ void acc8(float a[8], uint4 x, float v) {
    unsigned int u[4] = {x.x, x.y, x.z, x.w};
#pragma unroll
    for (int k = 0; k < 4; ++k) {
        a[2 * k]     = fmaf(v, __uint_as_float(u[k] << 16),          a[2 * k]);
        a[2 * k + 1] = fmaf(v, __uint_as_float(u[k] & 0xffff0000u), a[2 * k + 1]);
    }
}

// ---------------- CSR build ----------------

__global__ void init_bkt(int* __restrict__ bktCursor) {
    int t = threadIdx.x;
    if (t < NBKT) bktCursor[t] = t * ARENA_CAP;
}

// Phase 1: LDS multisplit into 32 fixed-capacity row-range bucket arenas
// (coalesced per-bucket segment writes -> no write amplification).
__global__ void bucket_kernel(const int* __restrict__ row, const int* __restrict__ col,
                              const float* __restrict__ vals, int* __restrict__ bktCursor,
                              int* __restrict__ rB, int* __restrict__ cB, float* __restrict__ vB) {
    __shared__ int cnt[NBKT];
    __shared__ int fill[NBKT];
    __shared__ int lofs[NBKT + 1];
    __shared__ int goff[NBKT];
    __shared__ int rS[P1_EDGES];
    __shared__ int cS[P1_EDGES];
    __shared__ float vS[P1_EDGES];
    __shared__ unsigned char bktS[P1_EDGES];

    int tid = threadIdx.x;
    int base = blockIdx.x * P1_EDGES;
    if (tid < NBKT) { cnt[tid] = 0; fill[tid] = 0; }
    __syncthreads();

    int r[4], c[4], b[4];
    float v[4];
#pragma unroll
    for (int i = 0; i < 4; ++i) {
        int e = base + tid + i * P1_THREADS;
        r[i] = row[e];
        c[i] = col[e];
        v[i] = vals[e];
        b[i] = r[i] / RSPAN;
        atomicAdd(&cnt[b[i]], 1);
    }
    __syncthreads();
    if (tid == 0) {
        int s = 0;
        for (int k = 0; k < NBKT; ++k) { lofs[k] = s; s += cnt[k]; }
        lofs[NBKT] = s;
    }
    __syncthreads();
    if (tid < NBKT) goff[tid] = atomicAdd(&bktCursor[tid], cnt[tid]);
    __syncthreads();
#pragma unroll
    for (int i = 0; i < 4; ++i) {
        int p = lofs[b[i]] + atomicAdd(&fill[b[i]], 1);
        rS[p] = r[i]; cS[p] = c[i]; vS[p] = v[i];
        bktS[p] = (unsigned char)b[i];
    }
    __syncthreads();
    for (int i = tid; i < P1_EDGES; i += P1_THREADS) {
        int bb = bktS[i];
        int g = goff[bb] + (i - lofs[bb]);
        rB[g] = rS[i];
        cB[g] = cS[i];
        vB[g] = vS[i];
    }
}

// Histogram from bucket arenas: 9375 LDS counters per block (37.5KB), then a
// coalesced contiguous atomic flush. No random device atomics.
__global__ void hist2_kernel(const int* __restrict__ rB, const int* __restrict__ bktCur,
                             int* __restrict__ counts) {
    __shared__ int lcnt[RSPAN];
    int b = blockIdx.x & (NBKT - 1);
    int sub = blockIdx.x >> 5;
    int tid = threadIdx.x;
    for (int i = tid; i < RSPAN; i += 256) lcnt[i] = 0;
    __syncthreads();
    int s = b * ARENA_CAP;
    int t = bktCur[b];
    int rbase = b * RSPAN;
    for (int i = s + sub * 256 + tid; i < t; i += HB * 256) {
        atomicAdd(&lcnt[rB[i] - rbase], 1);
    }
    __syncthreads();
    for (int i = tid; i < RSPAN; i += 256) {
        int c = lcnt[i];
        if (c) atomicAdd(&counts[rbase + i], c);
    }
}

// Exclusive scan, phase 1: per-block scan + block totals.
// Also reused (grid=1, blockSums=nullptr) as the phase-2 scan of block totals.
__global__ void scan_phase1(const int* __restrict__ in, int* __restrict__ out,
                            int* __restrict__ blockSums, int n) {
    __shared__ int sdata[SCAN_BLOCK];
    int tid = threadIdx.x;
    int base = blockIdx.x * SCAN_CHUNK + tid * SCAN_ITEMS;
    int pref[SCAN_ITEMS];
    int sum = 0;
#pragma unroll
    for (int i = 0; i < SCAN_ITEMS; ++i) {
        int idx = base + i;
        int v = (idx < n) ? in[idx] : 0;
        pref[i] = sum;
        sum += v;
    }
    sdata[tid] = sum;
    __syncthreads();
    for (int off = 1; off < SCAN_BLOCK; off <<= 1) {
        int t = (tid >= off) ? sdata[tid - off] : 0;
        __syncthreads();
        sdata[tid] += t;
        __syncthreads();
    }
    int texcl = (tid == 0) ? 0 : sdata[tid - 1];
    if (tid == SCAN_BLOCK - 1 && blockSums) blockSums[blockIdx.x] = sdata[SCAN_BLOCK - 1];
#pragma unroll
    for (int i = 0; i < SCAN_ITEMS; ++i) {
        int idx = base + i;
        if (idx < n) out[idx] = texcl + pref[i];
    }
}

__global__ void scan_phase3(int* __restrict__ out, const int* __restrict__ blockSums, int n) {
    int base = blockIdx.x * SCAN_CHUNK + threadIdx.x * SCAN_ITEMS;
    int add = blockSums[blockIdx.x];
#pragma unroll
    for (int i = 0; i < SCAN_ITEMS; ++i) {
        int idx = base + i;
        if (idx < n) out[idx] += add;
    }
}

// Phase 2: scatter one bucket's edges to final CSR positions; bucket via
// (blockIdx & 7) keeps each 2.4MB destination window XCD-local (L2 merges lines).
__global__ void scatter2_kernel(const int* __restrict__ rB, const int* __restrict__ cB,
                                const float* __restrict__ vB, const int* __restrict__ bktCur,
                                int* __restrict__ cursor, int2* __restrict__ edgeS,
                                int passBase) {
    int b = passBase + (blockIdx.x & 7);
    int sub = blockIdx.x >> 3;
    int s = b * ARENA_CAP;
    int t = bktCur[b];
    for (int i = s + sub * 256 + threadIdx.x; i < t; i += P2_BPB * 256) {
        int r = rB[i];
        int pos = atomicAdd(&cursor[r], 1);
        edgeS[pos] = make_int2(cB[i], __float_as_int(vB[i]));
    }
}

// ---------------- bf16 conversion ----------------
// e0b[j] (uint4 = 8 packed bf16) from concat(ue,ie).
__global__ void conv_e0(const float4* __restrict__ ue, const float4* __restrict__ ie,
                        uint4* __restrict__ e0b) {
    size_t j = (size_t)blockIdx.x * blockDim.x + threadIdx.x;  // uint4 index
    constexpr size_t N8 = (size_t)N * D8;
    constexpr size_t U16 = (size_t)U * D4;
    if (j >= N8) return;
    size_t f4 = j * 2;
    float4 f0, f1;
    if (f4 < U16) { f0 = ue[f4]; f1 = ue[f4 + 1]; }
    else          { f0 = ie[f4 - U16]; f1 = ie[f4 + 1 - U16]; }
    uint4 o;
    o.x = packbf(f0.x, f0.y); o.y = packbf(f0.z, f0.w);
    o.z = packbf(f1.x, f1.y); o.w = packbf(f1.z, f1.w);
    e0b[j] = o;
}

// ---------------- SpMM (bf16 gather, f32 accumulate) ----------------
// 8 lanes per node; each lane owns 8 dims (uint4 = 16B; 8 lanes = one 128B
// line per gathered row; 8 nodes per wave). Edge loop unrolled x4 so each
// wave keeps up to 32 gather lines in flight (MLP, the round-4 bottleneck).

__global__ void spmm_b(const int* __restrict__ rowPtr, const int2* __restrict__ edgeS,
                       const uint4* __restrict__ xb, uint4* __restrict__ yb) {
    int lane = threadIdx.x & 7;
    int n = blockIdx.x * 32 + (threadIdx.x >> 3);
    int s = rowPtr[n], t = rowPtr[n + 1];
    float a[8] = {0.f, 0.f, 0.f, 0.f, 0.f, 0.f, 0.f, 0.f};
    int e = s;
    for (; e + 4 <= t; e += 4) {
        int2 ev0 = edgeS[e];
        int2 ev1 = edgeS[e + 1];
        int2 ev2 = edgeS[e + 2];
        int2 ev3 = edgeS[e + 3];
        uint4 x0 = xb[(size_t)ev0.x * D8 + lane];
        uint4 x1 = xb[(size_t)ev1.x * D8 + lane];
        uint4 x2 = xb[(size_t)ev2.x * D8 + lane];
        uint4 x3 = xb[(size_t)ev3.x * D8 + lane];
        acc8(a, x0, __int_as_float(ev0.y));
        acc8(a, x1, __int_as_float(ev1.y));
        acc8(a, x2, __int_as_float(ev2.y));
        acc8(a, x3, __int_as_float(ev3.y));
    }
    for (; e < t; ++e) {
        int2 ev = edgeS[e];
        uint4 x = xb[(size_t)ev.x * D8 + lane];
        acc8(a, x, __int_as_float(ev.y));
    }
    uint4 o;
    o.x = packbf(a[0], a[1]); o.y = packbf(a[2], a[3]);
    o.z = packbf(a[4], a[5]); o.w = packbf(a[6], a[7]);
    yb[(size_t)n * D8 + lane] = o;
}

// Layer-3 SpMM fused with the full output epilogue (f32 outputs, nontemporal).
// out layout (float4 units): users[U*16] | items[I*16] | um0 um1 um2 (U*16 each) | im0 im1 im2 (I*16 each)
__global__ void spmm_final(const int* __restrict__ rowPtr, const int2* __restrict__ edgeS,
                           const uint4* __restrict__ h2b, const uint4* __restrict__ h1b,
                           const float4* __restrict__ ue, const float4* __restrict__ ie,
                           float4* __restrict__ out) {
    int lane = threadIdx.x & 7;
    int n = blockIdx.x * 32 + (threadIdx.x >> 3);
    int s = rowPtr[n], t = rowPtr[n + 1];
    float a[8] = {0.f, 0.f, 0.f, 0.f, 0.f, 0.f, 0.f, 0.f};
    int e = s;
    for (; e + 4 <= t; e += 4) {
        int2 ev0 = edgeS[e];
        int2 ev1 = edgeS[e + 1];
        int2 ev2 = edgeS[e + 2];
        int2 ev3 = edgeS[e + 3];
        uint4 x0 = h2b[(size_t)ev0.x * D8 + lane];
        uint4 x1 = h2b[(size_t)ev1.x * D8 + lane];
        uint4 x2 = h2b[(size_t)ev2.x * D8 + lane];
        uint4 x3 = h2b[(size_t)ev3.x * D8 + lane];
        acc8(a, x0, __int_as_float(ev0.y));
        acc8(a, x1, __int_as_float(ev1.y));
        acc8(a, x2, __int_as_float(ev2.y));
        acc8(a, x3, __int_as_float(ev3.y));
    }
    for (; e < t; ++e) {
        int2 ev = edgeS[e];
        uint4 x = h2b[(size_t)ev.x * D8 + lane];
        acc8(a, x, __int_as_float(ev.y));
    }

    size_t r8 = (size_t)n * D8 + lane;
    uint4 b1 = h1b[r8];
    uint4 b2 = h2b[r8];
    // e0 in f32 (exact): two float4 per lane.
    size_t fb = (n < U) ? ((size_t)n * D4 + lane * 2) : ((size_t)(n - U) * D4 + lane * 2);
    float4 e0a = (n < U) ? ue[fb] : ie[fb];
    float4 e0c = (n < U) ? ue[fb + 1] : ie[fb + 1];

    float e0v[8] = {e0a.x, e0a.y, e0a.z, e0a.w, e0c.x, e0c.y, e0c.z, e0c.w};
    unsigned int u1[4] = {b1.x, b1.y, b1.z, b1.w};
    unsigned int u2[4] = {b2.x, b2.y, b2.z, b2.w};
    float c1[8], c2[8], c3[8];
#pragma unroll
    for (int k = 0; k < 4; ++k) {
        c1[2 * k]     = e0v[2 * k]     + __uint_as_float(u1[k] << 16);
        c1[2 * k + 1] = e0v[2 * k + 1] + __uint_as_float(u1[k] & 0xffff0000u);
        c2[2 * k]     = c1[2 * k]      + __uint_as_float(u2[k] << 16);
        c2[2 * k + 1] = c1[2 * k + 1]  + __uint_as_float(u2[k] & 0xffff0000u);
    }
#pragma unroll
    for (int k = 0; k < 8; ++k) c3[k] = c2[k] + a[k];

    float4 um0a, um0b, um1a, um1b, ma, mb;
    um0a.x = c1[0] * 0.5f;  um0a.y = c1[1] * 0.5f;  um0a.z = c1[2] * 0.5f;  um0a.w = c1[3] * 0.5f;
    um0b.x = c1[4] * 0.5f;  um0b.y = c1[5] * 0.5f;  um0b.z = c1[6] * 0.5f;  um0b.w = c1[7] * 0.5f;
    um1a.x = c2[0] / 3.0f;  um1a.y = c2[1] / 3.0f;  um1a.z = c2[2] / 3.0f;  um1a.w = c2[3] / 3.0f;
    um1b.x = c2[4] / 3.0f;  um1b.y = c2[5] / 3.0f;  um1b.z = c2[6] / 3.0f;  um1b.w = c2[7] / 3.0f;
    ma.x   = c3[0] * 0.25f; ma.y   = c3[1] * 0.25f; ma.z   = c3[2] * 0.25f; ma.w   = c3[3] * 0.25f;
    mb.x   = c3[4] * 0.25f; mb.y   = c3[5] * 0.25f; mb.z   = c3[6] * 0.25f; mb.w   = c3[7] * 0.25f;

    constexpr size_t N16 = (size_t)N * D4;
    constexpr size_t U16 = (size_t)U * D4;
    constexpr size_t I16 = (size_t)I * D4;
    if (n < U) {
        size_t r = (size_t)n * D4 + lane * 2;
        nt_store4(ma,   &out[r]);                    // users
        nt_store4(mb,   &out[r + 1]);
        nt_store4(um0a, &out[N16 + r]);              // users_mean0
        nt_store4(um0b, &out[N16 + r + 1]);
        nt_store4(um1a, &out[N16 + U16 + r]);        // users_mean1
        nt_store4(um1b, &out[N16 + U16 + r + 1]);
        nt_store4(ma,   &out[N16 + 2 * U16 + r]);    // users_mean2 == users
        nt_store4(mb,   &out[N16 + 2 * U16 + r + 1]);
    } else {
        size_t r = (size_t)(n - U) * D4 + lane * 2;
        nt_store4(ma,   &out[U16 + r]);                     // items
        nt_store4(mb,   &out[U16 + r + 1]);
        nt_store4(um0a, &out[N16 + 3 * U16 + r]);           // items_mean0
        nt_store4(um0b, &out[N16 + 3 * U16 + r + 1]);
        nt_store4(um1a, &out[N16 + 3 * U16 + I16 + r]);     // items_mean1
        nt_store4(um1b, &out[N16 + 3 * U16 + I16 + r + 1]);
        nt_store4(ma,   &out[N16 + 3 * U16 + 2 * I16 + r]); // items_mean2
        nt_store4(mb,   &out[N16 + 3 * U16 + 2 * I16 + r + 1]);
    }
}

extern "C" void kernel_launch(void* const* d_in, const int* in_sizes, int n_in,
                              void* d_out, int out_size, void* d_ws, size_t ws_size,
                              hipStream_t stream) {
    const float* ue   = (const float*)d_in[0];
    const float* ie   = (const float*)d_in[1];
    const int*   row  = (const int*)d_in[2];
    const int*   col  = (const int*)d_in[3];
    const float* vals = (const float*)d_in[4];

    char* ws = (char*)d_ws;
    size_t off = 0;
    // blob0: 119MB arenas (rB|cB|vB, CAP-sized). Second life: e0b|h1b|h2b (38.4MB each).
    constexpr size_t ARENA_TOTAL = (size_t)NBKT * ARENA_CAP;   // 9.92M entries
    char* blob0 = ws + off; off += (size_t)3 * ARENA_TOTAL * 4;
    int2* edgeS  = (int2*)(ws + off); off += (size_t)E * 8;          // 76.8 MB
    int*  counts = (int*)(ws + off);  off += (size_t)(N + 1) * 4;    // counts, then cursor
    int*  rowPtr = (int*)(ws + off);  off += (size_t)(N + 1) * 4;
    int*  bsums  = (int*)(ws + off);  off += 4096;
    int*  bktCur = (int*)(ws + off);  off += 256;

    int*   rB  = (int*)blob0;
    int*   cB  = (int*)(blob0 + (size_t)ARENA_TOTAL * 4);
    float* vB  = (float*)(blob0 + (size_t)2 * ARENA_TOTAL * 4);
    uint4* e0b = (uint4*)blob0;                        // N*64 bf16 = 38.4MB
    uint4* h1b = (uint4*)(blob0 + (size_t)E * 4);
    uint4* h2b = (uint4*)(blob0 + (size_t)2 * E * 4);

    // ---- CSR build (rebuilt every call; deterministic work) ----
    hipMemsetAsync(counts, 0, (size_t)(N + 1) * 4, stream);
    init_bkt<<<1, 64, 0, stream>>>(bktCur);
    bucket_kernel<<<E / P1_EDGES, P1_THREADS, 0, stream>>>(row, col, vals, bktCur, rB, cB, vB);
    hist2_kernel<<<NBKT * HB, 256, 0, stream>>>(rB, bktCur, counts);
    const int nScan = N + 1;
    const int nB = (nScan + SCAN_CHUNK - 1) / SCAN_CHUNK;   // 293
    scan_phase1<<<nB, SCAN_BLOCK, 0, stream>>>(counts, rowPtr, bsums, nScan);
    scan_phase1<<<1, SCAN_BLOCK, 0, stream>>>(bsums, bsums, nullptr, nB);
    scan_phase3<<<nB, SCAN_BLOCK, 0, stream>>>(rowPtr, bsums, nScan);
    hipMemcpyAsync(counts, rowPtr, (size_t)N * 4, hipMemcpyDeviceToDevice, stream); // cursor

    for (int pass = 0; pass < 4; ++pass) {
        scatter2_kernel<<<8 * P2_BPB, 256, 0, stream>>>(rB, cB, vB, bktCur, counts, edgeS,
                                                        pass * 8);
    }

    // ---- bf16 e0 (arenas dead after scatter; e0b aliases rB region) ----
    const size_t n8 = (size_t)N * D8;
    conv_e0<<<(int)((n8 + 255) / 256), 256, 0, stream>>>((const float4*)ue, (const float4*)ie,
                                                         e0b);

    // ---- 3 SpMM layers (layer 3 fused with output epilogue) ----
    const int spmmBlocks = N / 32;  // 9375, 32 nodes per 256-thread block
    spmm_b<<<spmmBlocks, 256, 0, stream>>>(rowPtr, edgeS, e0b, h1b);
    spmm_b<<<spmmBlocks, 256, 0, stream>>>(rowPtr, edgeS, h1b, h2b);
    spmm_final<<<spmmBlocks, 256, 0, stream>>>(rowPtr, edgeS, h2b, h1b,
                                               (const float4*)ue, (const float4*)ie,
                                               (float4*)d_out);
}